// Round 13
// baseline (751.476 us; speedup 1.0000x reference)
//
#include <hip/hip_runtime.h>

typedef unsigned int uint;
typedef float vfloat4 __attribute__((ext_vector_type(4)));

#define B_ROWS 128
#define T_SAMP 160000
#define NSEC 3
#define LCH 20     // samples per chunk (one lane)
#define NF4 5      // float4 loads per lane
#define RST 21     // LDS transpose row stride (odd -> conflict-free)
#define SUPW 1280  // samples per superchunk (64 lanes * 20)
#define NSUP 125   // superchunks per row
#define NSC (B_ROWS * NSUP)  // 16000
#define WPB 4
// mats layout (floats): [0..215]   P_k = M^(2^k), M = A^20, k=0..5
//                       [216..467] Q_k = (M^64)^(2^k), k=0..6
//                       [468..587] Gm: g_t = c^T A^t, t=0..19 (row-major [t][e])

struct Coefs { float b0[NSEC], b1[NSEC], b2[NSEC], a1[NSEC], a2[NSEC]; };

__device__ __forceinline__ void load_coefs(const float* __restrict__ sos, Coefs& c) {
#pragma unroll
  for (int s = 0; s < NSEC; ++s) {
    c.b0[s] = sos[s * 6 + 0];
    c.b1[s] = sos[s * 6 + 1];
    c.b2[s] = sos[s * 6 + 2];
    c.a1[s] = sos[s * 6 + 4];
    c.a2[s] = sos[s * 6 + 5];
  }
}

// One DF2T cascade time-step, same op order as the reference.
__device__ __forceinline__ float df2t_step(const Coefs& c, float z[6], float x) {
  float y = x;
#pragma unroll
  for (int s = 0; s < NSEC; ++s) {
    float out = fmaf(c.b0[s], y, z[2 * s]);
    float t0  = fmaf(c.b1[s], y, z[2 * s + 1]);
    z[2 * s]     = fmaf(-c.a1[s], out, t0);
    float t1  = c.b2[s] * y;
    z[2 * s + 1] = fmaf(-c.a2[s], out, t1);
    y = out;
  }
  return y;
}

// Affine combine f := f + P*t; cascade matrices are 2x2-block lower-triangular.
__device__ __forceinline__ void tri_combine(float f[6], const float* __restrict__ P,
                                            const float t[6]) {
  float nf[6];
#pragma unroll
  for (int e = 0; e < 6; ++e) {
    float acc = f[e];
    const int kmax = ((e >> 1) << 1) + 2;
#pragma unroll
    for (int kk = 0; kk < 6; ++kk)
      if (kk < kmax) acc = fmaf(P[e * 6 + kk], t[kk], acc);
    nf[e] = acc;
  }
#pragma unroll
  for (int e = 0; e < 6; ++e) f[e] = nf[e];
}

// Lane-distributed 6x6 matmul: lane e<36 holds element (e/6, e%6).
__device__ __forceinline__ float dmm6(float a, float b, int i, int j) {
  float s = 0.f;
#pragma unroll
  for (int k = 0; k < 6; ++k)
    s = fmaf(__shfl(a, i * 6 + k), __shfl(b, k * 6 + j), s);
  return s;
}

// In-wave reduce of <=64 affine offsets: lane l holds val_l; result (lane 0)
// = sum_l Q^l * val_l, using Qm[k] = Q^(2^k). Out-of-window lanes hold 0.
__device__ __forceinline__ void window_reduce(float val[6], const float* __restrict__ Qm,
                                              int lane) {
#pragma unroll
  for (int k = 0; k < 6; ++k) {
    float t[6];
#pragma unroll
    for (int e = 0; e < 6; ++e) t[e] = __shfl_down(val[e], 1 << k);
    const bool ok = (lane + (1 << k)) < 64;
#pragma unroll
    for (int e = 0; e < 6; ++e) t[e] = ok ? t[e] : 0.f;
    tri_combine(val, Qm + k * 36, t);
  }
}

// Init: zero status+ticket; block 0 wave 0 also computes all matrices.
__global__ __launch_bounds__(256) void init_kernel(const float* __restrict__ sos,
                                                   uint* __restrict__ status,
                                                   uint* __restrict__ ticket,
                                                   float* __restrict__ mats) {
  __shared__ float Ash[36];
  __shared__ float As5[5 * 36];
  const int gid = blockIdx.x * blockDim.x + threadIdx.x;
  if (gid == 0) *ticket = 0u;
  if (gid < NSC) status[gid] = 0u;

  if (blockIdx.x == 0 && threadIdx.x < 64) {
    const int lane = threadIdx.x;
    Coefs cf; load_coefs(sos, cf);
    if (lane == 0) {  // build A with compile-time indices only (rule #20)
      float A[36];
#pragma unroll
      for (int jc = 0; jc < 6; ++jc) {
        float z[6] = {0.f, 0.f, 0.f, 0.f, 0.f, 0.f};
        z[jc] = 1.f;
        df2t_step(cf, z, 0.f);
#pragma unroll
        for (int ic = 0; ic < 6; ++ic) A[ic * 6 + jc] = z[ic];
      }
#pragma unroll
      for (int q = 0; q < 36; ++q) Ash[q] = A[q];
    }
    // same wave: LDS in-order, no barrier needed
    const int e = (lane < 36) ? lane : 0;
    const int mi = e / 6, mj = e % 6;
    float a1p = Ash[e];
    float a2p  = dmm6(a1p, a1p, mi, mj);
    float a4p  = dmm6(a2p, a2p, mi, mj);
    float a8p  = dmm6(a4p, a4p, mi, mj);
    float a16p = dmm6(a8p, a8p, mi, mj);
    if (lane < 36) {
      As5[lane] = a1p; As5[36 + lane] = a2p; As5[72 + lane] = a4p;
      As5[108 + lane] = a8p; As5[144 + lane] = a16p;
    }
    float pk = dmm6(a16p, a4p, mi, mj);  // M = A^20
    if (lane < 36) mats[lane] = pk;
#pragma unroll
    for (int k = 1; k < 6; ++k) {
      pk = dmm6(pk, pk, mi, mj);
      if (lane < 36) mats[k * 36 + lane] = pk;
    }
    float q = dmm6(pk, pk, mi, mj);      // Q = M^64
    if (lane < 36) mats[216 + lane] = q;
#pragma unroll
    for (int k = 1; k < 7; ++k) {
      q = dmm6(q, q, mi, mj);
      if (lane < 36) mats[216 + k * 36 + lane] = q;
    }
    // g-table: g_t = c^T A^t, c = [b0_1*b0_2, 0, b0_2, 0, 1, 0]
    if (lane < LCH) {
      float g[6] = {cf.b0[1] * cf.b0[2], 0.f, cf.b0[2], 0.f, 1.f, 0.f};
#pragma unroll
      for (int k = 0; k < 5; ++k) {
        if (lane & (1 << k)) {
          float ng[6];
#pragma unroll
          for (int j = 0; j < 6; ++j) {
            float acc = 0.f;
#pragma unroll
            for (int i = 0; i < 6; ++i) acc = fmaf(g[i], As5[k * 36 + i * 6 + j], acc);
            ng[j] = acc;
          }
#pragma unroll
          for (int j = 0; j < 6; ++j) g[j] = ng[j];
        }
      }
#pragma unroll
      for (int j = 0; j < 6; ++j) mats[468 + lane * 6 + j] = g[j];
    }
  }
}

__global__ __launch_bounds__(256) void fused_kernel(
    const float* __restrict__ x, const float* __restrict__ sos,
    const float* __restrict__ mats, float* __restrict__ y,
    uint* __restrict__ ticket, uint* __restrict__ status,
    float* __restrict__ aggf) {
  __shared__ float Tr[WPB][64 * RST];
  __shared__ uint tkbase_sh;
  const int tid = threadIdx.x, w = tid >> 6, lane = tid & 63;
  Coefs cf; load_coefs(sos, cf);

  // ONE ticket RMW per block (kills the 16000-RMW hot line); waves derive tk.
  if (tid == 0) tkbase_sh = atomicAdd(ticket, (uint)WPB);
  __syncthreads();
  const uint tk = tkbase_sh + (uint)w;  // consecutive rows, same s: independent
  const int r = (int)(tk & 127u);
  const int s = (int)(tk >> 7);

  const size_t base = (size_t)r * T_SAMP + (size_t)s * SUPW;
  const float4* src = reinterpret_cast<const float4*>(x + base + (size_t)lane * LCH);
  float4 v0 = src[0], v1 = src[1], v2 = src[2], v3 = src[3], v4 = src[4];

  // zero-state pass capturing y_zero in-place; f = chunk zero-state final
  float f[6] = {0.f, 0.f, 0.f, 0.f, 0.f, 0.f};
  v0.x = df2t_step(cf, f, v0.x); v0.y = df2t_step(cf, f, v0.y);
  v0.z = df2t_step(cf, f, v0.z); v0.w = df2t_step(cf, f, v0.w);
  v1.x = df2t_step(cf, f, v1.x); v1.y = df2t_step(cf, f, v1.y);
  v1.z = df2t_step(cf, f, v1.z); v1.w = df2t_step(cf, f, v1.w);
  v2.x = df2t_step(cf, f, v2.x); v2.y = df2t_step(cf, f, v2.y);
  v2.z = df2t_step(cf, f, v2.z); v2.w = df2t_step(cf, f, v2.w);
  v3.x = df2t_step(cf, f, v3.x); v3.y = df2t_step(cf, f, v3.y);
  v3.z = df2t_step(cf, f, v3.z); v3.w = df2t_step(cf, f, v3.w);
  v4.x = df2t_step(cf, f, v4.x); v4.y = df2t_step(cf, f, v4.y);
  v4.z = df2t_step(cf, f, v4.z); v4.w = df2t_step(cf, f, v4.w);

  // zero-seeded wave scan of per-chunk finals
#pragma unroll
  for (int k = 0; k < 6; ++k) {
    float t6[6];
#pragma unroll
    for (int e = 0; e < 6; ++e) t6[e] = __shfl_up(f[e], 1 << k);
    if (lane >= (1 << k)) tri_combine(f, mats + k * 36, t6);
  }
  float excl[6];
#pragma unroll
  for (int e = 0; e < 6; ++e) {
    float tt = __shfl_up(f[e], 1);
    excl[e] = (lane == 0) ? 0.f : tt;
  }
  float Fb[6];  // superchunk zero-state aggregate
#pragma unroll
  for (int e = 0; e < 6; ++e) Fb[e] = __shfl(f[e], 63);

  // ---- HARDENED PUBLISH: must be ISA-complete before any poll issues ----
  if (lane == 0) {
#pragma unroll
    for (int e = 0; e < 6; ++e)
      __hip_atomic_store(&aggf[(size_t)tk * 6 + e], Fb[e],
                         __ATOMIC_RELAXED, __HIP_MEMORY_SCOPE_AGENT);
  }
  __builtin_amdgcn_fence(__ATOMIC_RELEASE, "agent");  // aggf visible before status
  if (lane == 0)
    __hip_atomic_store(&status[tk], 1u, __ATOMIC_RELAXED, __HIP_MEMORY_SCOPE_AGENT);
  asm volatile("s_waitcnt vmcnt(0)" ::: "memory");    // store has LEFT the wave
  __builtin_amdgcn_sched_barrier(0);                  // no compiler motion past here

  // AGG-only wave-parallel lookback: z0 = sum_{d=1..s} Q^(d-1) * F(s-d)
  float z0[6] = {0.f, 0.f, 0.f, 0.f, 0.f, 0.f};
  if (s > 0) {
    const float* Qm = mats + 216;
    float acc[6];
    {
      const int nv = (s < 64) ? s : 64;
      const bool act = lane < nv;
      const size_t pt = (size_t)tk - 128u * (uint)(lane + 1);
      if (act) {
        while (__hip_atomic_fetch_add(&status[pt], 0u, __ATOMIC_RELAXED,
                                      __HIP_MEMORY_SCOPE_AGENT) == 0u)
          __builtin_amdgcn_s_sleep(4);
      }
      __builtin_amdgcn_fence(__ATOMIC_ACQUIRE, "agent");
      float val[6];
#pragma unroll
      for (int e = 0; e < 6; ++e)
        val[e] = act ? __hip_atomic_load(&aggf[pt * 6 + e], __ATOMIC_RELAXED,
                                         __HIP_MEMORY_SCOPE_AGENT)
                     : 0.f;
      window_reduce(val, Qm, lane);
#pragma unroll
      for (int e = 0; e < 6; ++e) acc[e] = val[e];  // valid on lane 0
    }
    if (s > 64) {  // distances 65..s (s <= 124 -> one extra window)
      const int nv = s - 64;
      const bool act = lane < nv;
      const size_t pt = (size_t)tk - 128u * (uint)(lane + 65);
      if (act) {
        while (__hip_atomic_fetch_add(&status[pt], 0u, __ATOMIC_RELAXED,
                                      __HIP_MEMORY_SCOPE_AGENT) == 0u)
          __builtin_amdgcn_s_sleep(4);
      }
      __builtin_amdgcn_fence(__ATOMIC_ACQUIRE, "agent");
      float val[6];
#pragma unroll
      for (int e = 0; e < 6; ++e)
        val[e] = act ? __hip_atomic_load(&aggf[pt * 6 + e], __ATOMIC_RELAXED,
                                         __HIP_MEMORY_SCOPE_AGENT)
                     : 0.f;
      window_reduce(val, Qm, lane);
      tri_combine(acc, Qm + 6 * 36, val);  // acc += Q^64 * window1 (lane 0)
    }
#pragma unroll
    for (int e = 0; e < 6; ++e) z0[e] = __shfl(acc[e], 0);
  }

  // per-lane chunk-start state: zs = excl + M^lane * z0 (binary decomposition)
  float zs[6];
  if (s > 0) {
    float wv[6];
#pragma unroll
    for (int e = 0; e < 6; ++e) wv[e] = z0[e];
#pragma unroll
    for (int k = 0; k < 6; ++k) {
      if ((lane >> k) & 1) {
        float nw[6];
#pragma unroll
        for (int e = 0; e < 6; ++e) {
          float a = 0.f;
          const int kmax = ((e >> 1) << 1) + 2;
#pragma unroll
          for (int kk = 0; kk < 6; ++kk)
            if (kk < kmax) a = fmaf(mats[k * 36 + e * 6 + kk], wv[kk], a);
          nw[e] = a;
        }
#pragma unroll
        for (int e = 0; e < 6; ++e) wv[e] = nw[e];
      }
    }
#pragma unroll
    for (int e = 0; e < 6; ++e) zs[e] = excl[e] + wv[e];
  } else {
#pragma unroll
    for (int e = 0; e < 6; ++e) zs[e] = excl[e];
  }

  // linear correction y = y_zero + g_t . zs -> own-wave LDS transpose rows
  const float* Gm = mats + 468;
  float* myrow = &Tr[w][lane * RST];
  auto corr = [&](int tl, float yz) {
    float a = yz;
#pragma unroll
    for (int e = 0; e < 6; ++e) a = fmaf(Gm[tl * 6 + e], zs[e], a);
    myrow[tl] = a;
  };
  corr(0, v0.x);  corr(1, v0.y);  corr(2, v0.z);  corr(3, v0.w);
  corr(4, v1.x);  corr(5, v1.y);  corr(6, v1.z);  corr(7, v1.w);
  corr(8, v2.x);  corr(9, v2.y);  corr(10, v2.z); corr(11, v2.w);
  corr(12, v3.x); corr(13, v3.y); corr(14, v3.z); corr(15, v3.w);
  corr(16, v4.x); corr(17, v4.y); corr(18, v4.z); corr(19, v4.w);

  float* dst = y + base;
#pragma unroll
  for (int i2 = 0; i2 < NF4; ++i2) {
    int q = i2 * 64 + lane, k = q / NF4, m = q - k * NF4;
    vfloat4 w4;
    w4.x = Tr[w][k * RST + m * 4 + 0];
    w4.y = Tr[w][k * RST + m * 4 + 1];
    w4.z = Tr[w][k * RST + m * 4 + 2];
    w4.w = Tr[w][k * RST + m * 4 + 3];
    __builtin_nontemporal_store(w4, reinterpret_cast<vfloat4*>(dst + 4 * q));
  }
}

extern "C" void kernel_launch(void* const* d_in, const int* in_sizes, int n_in,
                              void* d_out, int out_size, void* d_ws, size_t ws_size,
                              hipStream_t stream) {
  const float* x = (const float*)d_in[0];
  const float* sos = (const float*)d_in[1];
  float* y = (float*)d_out;

  uint* ticket = (uint*)d_ws;              // [16]
  uint* status = ticket + 16;              // [NSC]
  float* aggf = (float*)(status + NSC);    // [NSC][6]
  float* mats = aggf + (size_t)NSC * 6;    // [588]

  hipLaunchKernelGGL(init_kernel, dim3((NSC + 255) / 256), dim3(256), 0, stream,
                     sos, status, ticket, mats);
  hipLaunchKernelGGL(fused_kernel, dim3(NSC / WPB), dim3(256), 0, stream,
                     x, sos, mats, y, ticket, status, aggf);
}

// Round 14
// 62.526 us; speedup vs baseline: 12.0186x; 12.0186x over previous
//
#include <hip/hip_runtime.h>

typedef float vfloat4 __attribute__((ext_vector_type(4)));

#define B_ROWS 128
#define T_SAMP 160000
#define NSEC 3
#define LCH 20     // samples per chunk (one lane)
#define NF4 5      // float4 loads per lane
#define RST 21     // LDS transpose row stride (odd -> conflict-free)
#define SUPW 1280  // samples per superchunk (64 lanes * 20)
#define NSUP 125   // superchunks per row
#define NSC (B_ROWS * NSUP)  // 16000
#define WPB 4
// mats layout (floats): [0..215]   P_k = M^(2^k), M = A^20, k=0..5
//                       [216..467] Q_k = (M^64)^(2^k), k=0..6
//                       [468..587] Gm: g_t = c^T A^t, t=0..19 (row-major [t][e])

struct Coefs { float b0[NSEC], b1[NSEC], b2[NSEC], a1[NSEC], a2[NSEC]; };

__device__ __forceinline__ void load_coefs(const float* __restrict__ sos, Coefs& c) {
#pragma unroll
  for (int s = 0; s < NSEC; ++s) {
    c.b0[s] = sos[s * 6 + 0];
    c.b1[s] = sos[s * 6 + 1];
    c.b2[s] = sos[s * 6 + 2];
    c.a1[s] = sos[s * 6 + 4];
    c.a2[s] = sos[s * 6 + 5];
  }
}

// One DF2T cascade time-step, same op order as the reference.
__device__ __forceinline__ float df2t_step(const Coefs& c, float z[6], float x) {
  float y = x;
#pragma unroll
  for (int s = 0; s < NSEC; ++s) {
    float out = fmaf(c.b0[s], y, z[2 * s]);
    float t0  = fmaf(c.b1[s], y, z[2 * s + 1]);
    z[2 * s]     = fmaf(-c.a1[s], out, t0);
    float t1  = c.b2[s] * y;
    z[2 * s + 1] = fmaf(-c.a2[s], out, t1);
    y = out;
  }
  return y;
}

// Affine combine f := f + P*t; cascade matrices are 2x2-block lower-triangular.
__device__ __forceinline__ void tri_combine(float f[6], const float* __restrict__ P,
                                            const float t[6]) {
  float nf[6];
#pragma unroll
  for (int e = 0; e < 6; ++e) {
    float acc = f[e];
    const int kmax = ((e >> 1) << 1) + 2;
#pragma unroll
    for (int kk = 0; kk < 6; ++kk)
      if (kk < kmax) acc = fmaf(P[e * 6 + kk], t[kk], acc);
    nf[e] = acc;
  }
#pragma unroll
  for (int e = 0; e < 6; ++e) f[e] = nf[e];
}

// Lane-distributed 6x6 matmul: lane e<36 holds element (e/6, e%6).
__device__ __forceinline__ float dmm6(float a, float b, int i, int j) {
  float s = 0.f;
#pragma unroll
  for (int k = 0; k < 6; ++k)
    s = fmaf(__shfl(a, i * 6 + k), __shfl(b, k * 6 + j), s);
  return s;
}

// Setup: one wave computes all transition-matrix powers + g-table -> mats.
__global__ __launch_bounds__(64) void setup_kernel(const float* __restrict__ sos,
                                                   float* __restrict__ mats) {
  __shared__ float Ash[36];
  __shared__ float As5[5 * 36];
  const int lane = threadIdx.x;
  Coefs cf; load_coefs(sos, cf);
  if (lane == 0) {  // build A with compile-time indices only (rule #20)
    float A[36];
#pragma unroll
    for (int jc = 0; jc < 6; ++jc) {
      float z[6] = {0.f, 0.f, 0.f, 0.f, 0.f, 0.f};
      z[jc] = 1.f;
      df2t_step(cf, z, 0.f);
#pragma unroll
      for (int ic = 0; ic < 6; ++ic) A[ic * 6 + jc] = z[ic];
    }
#pragma unroll
    for (int q = 0; q < 36; ++q) Ash[q] = A[q];
  }
  __syncthreads();

  const int e = (lane < 36) ? lane : 0;
  const int mi = e / 6, mj = e % 6;
  float a1p = Ash[e];
  float a2p  = dmm6(a1p, a1p, mi, mj);
  float a4p  = dmm6(a2p, a2p, mi, mj);
  float a8p  = dmm6(a4p, a4p, mi, mj);
  float a16p = dmm6(a8p, a8p, mi, mj);
  if (lane < 36) {
    As5[lane] = a1p; As5[36 + lane] = a2p; As5[72 + lane] = a4p;
    As5[108 + lane] = a8p; As5[144 + lane] = a16p;
  }
  float pk = dmm6(a16p, a4p, mi, mj);  // M = A^20
  if (lane < 36) mats[lane] = pk;
#pragma unroll
  for (int k = 1; k < 6; ++k) {
    pk = dmm6(pk, pk, mi, mj);
    if (lane < 36) mats[k * 36 + lane] = pk;
  }
  float q = dmm6(pk, pk, mi, mj);      // Q = M^64
  if (lane < 36) mats[216 + lane] = q;
#pragma unroll
  for (int k = 1; k < 7; ++k) {
    q = dmm6(q, q, mi, mj);
    if (lane < 36) mats[216 + k * 36 + lane] = q;
  }
  // g-table: g_t = c^T A^t, c = [b0_1*b0_2, 0, b0_2, 0, 1, 0]
  if (lane < LCH) {
    float g[6] = {cf.b0[1] * cf.b0[2], 0.f, cf.b0[2], 0.f, 1.f, 0.f};
#pragma unroll
    for (int k = 0; k < 5; ++k) {
      if (lane & (1 << k)) {
        float ng[6];
#pragma unroll
        for (int j = 0; j < 6; ++j) {
          float acc = 0.f;
#pragma unroll
          for (int i = 0; i < 6; ++i) acc = fmaf(g[i], As5[k * 36 + i * 6 + j], acc);
          ng[j] = acc;
        }
#pragma unroll
        for (int j = 0; j < 6; ++j) g[j] = ng[j];
      }
    }
#pragma unroll
    for (int j = 0; j < 6; ++j) mats[468 + lane * 6 + j] = g[j];
  }
}

// Pass 1: register-direct, ZERO LDS. Zero-state final per chunk, wave scan,
// lane 63 writes superchunk aggregate. (r10-verified)
__global__ __launch_bounds__(256) void pass1_kernel(const float* __restrict__ x,
                                                    const float* __restrict__ sos,
                                                    const float* __restrict__ mats,
                                                    float* __restrict__ Fsup) {
  const int tid = threadIdx.x, w = tid >> 6, lane = tid & 63;
  Coefs cf; load_coefs(sos, cf);
  const int S = blockIdx.x * WPB + w;
  const int r = S / NSUP, s = S - r * NSUP;
  const float4* src = reinterpret_cast<const float4*>(
      x + (size_t)r * T_SAMP + (size_t)s * SUPW + (size_t)lane * LCH);
  float4 v0 = src[0], v1 = src[1], v2 = src[2], v3 = src[3], v4 = src[4];

  float f[6] = {0.f, 0.f, 0.f, 0.f, 0.f, 0.f};
  df2t_step(cf, f, v0.x); df2t_step(cf, f, v0.y); df2t_step(cf, f, v0.z); df2t_step(cf, f, v0.w);
  df2t_step(cf, f, v1.x); df2t_step(cf, f, v1.y); df2t_step(cf, f, v1.z); df2t_step(cf, f, v1.w);
  df2t_step(cf, f, v2.x); df2t_step(cf, f, v2.y); df2t_step(cf, f, v2.z); df2t_step(cf, f, v2.w);
  df2t_step(cf, f, v3.x); df2t_step(cf, f, v3.y); df2t_step(cf, f, v3.z); df2t_step(cf, f, v3.w);
  df2t_step(cf, f, v4.x); df2t_step(cf, f, v4.y); df2t_step(cf, f, v4.z); df2t_step(cf, f, v4.w);

#pragma unroll
  for (int k = 0; k < 6; ++k) {
    float t6[6];
#pragma unroll
    for (int e = 0; e < 6; ++e) t6[e] = __shfl_up(f[e], 1 << k);
    if (lane >= (1 << k)) tri_combine(f, mats + k * 36, t6);
  }
  if (lane == 63) {
    float* fo = Fsup + (size_t)S * 6;
#pragma unroll
    for (int e = 0; e < 6; ++e) fo[e] = f[e];
  }
}

// Middle: per-row scan over NSUP superchunks: z[s+1] = Q z[s] + Fsup[s]. (r10)
__global__ __launch_bounds__(64) void middle_scan(const float* __restrict__ Fsup,
                                                  const float* __restrict__ mats,
                                                  float* __restrict__ zsup) {
  const float* Qm = mats + 216;
  const int r = blockIdx.x, lane = threadIdx.x;
  const float* frow = Fsup + (size_t)r * NSUP * 6;
  float fc[2][6];
#pragma unroll
  for (int jj = 0; jj < 2; ++jj) {
    int c = 2 * lane + jj;
#pragma unroll
    for (int e = 0; e < 6; ++e) fc[jj][e] = (c < NSUP) ? frow[c * 6 + e] : 0.f;
  }
  float s[6] = {0.f, 0.f, 0.f, 0.f, 0.f, 0.f};
#pragma unroll
  for (int jj = 0; jj < 2; ++jj) {
    float ns[6];
#pragma unroll
    for (int e = 0; e < 6; ++e) {
      float acc = fc[jj][e];
#pragma unroll
      for (int kk = 0; kk < 6; ++kk) acc = fmaf(Qm[e * 6 + kk], s[kk], acc);
      ns[e] = acc;
    }
#pragma unroll
    for (int e = 0; e < 6; ++e) s[e] = ns[e];
  }
#pragma unroll
  for (int k = 0; k < 6; ++k) {
    float t[6];
#pragma unroll
    for (int e = 0; e < 6; ++e) t[e] = __shfl_up(s[e], 1 << k);
    if (lane >= (1 << k)) tri_combine(s, Qm + (k + 1) * 36, t);
  }
  float z[6];
#pragma unroll
  for (int e = 0; e < 6; ++e) {
    float t = __shfl_up(s[e], 1);
    z[e] = (lane == 0) ? 0.f : t;
  }
  float* zrow = zsup + (size_t)r * NSUP * 6;
#pragma unroll
  for (int jj = 0; jj < 2; ++jj) {
    int c = 2 * lane + jj;
    if (c < NSUP) {
#pragma unroll
      for (int e = 0; e < 6; ++e) zrow[c * 6 + e] = z[e];
    }
    float nz[6];
#pragma unroll
    for (int e = 0; e < 6; ++e) {
      float acc = fc[jj][e];
#pragma unroll
      for (int kk = 0; kk < 6; ++kk) acc = fmaf(Qm[e * 6 + kk], z[kk], acc);
      nz[e] = acc;
    }
#pragma unroll
    for (int e = 0; e < 6; ++e) z[e] = nz[e];
  }
}

// Pass 2: ONE df2t chain (captures y_zero in-place) + fold-scan (excl output
// IS the true chunk-start state) + g-correction epilogue (no second chain).
__global__ __launch_bounds__(256) void pass2_kernel(const float* __restrict__ x,
                                                    const float* __restrict__ sos,
                                                    const float* __restrict__ mats,
                                                    const float* __restrict__ zsup,
                                                    float* __restrict__ y) {
  __shared__ float Tr[WPB][64 * RST];
  const int tid = threadIdx.x, w = tid >> 6, lane = tid & 63;
  Coefs cf; load_coefs(sos, cf);
  const int S = blockIdx.x * WPB + w;
  const int r = S / NSUP, s = S - r * NSUP;
  const size_t base = (size_t)r * T_SAMP + (size_t)s * SUPW;
  const float4* src = reinterpret_cast<const float4*>(x + base + (size_t)lane * LCH);
  float4 v0 = src[0], v1 = src[1], v2 = src[2], v3 = src[3], v4 = src[4];

  float z0[6];
  const float* zp = zsup + (size_t)S * 6;
#pragma unroll
  for (int e = 0; e < 6; ++e) z0[e] = zp[e];

  // zero-state pass capturing y_zero in-place; f = chunk zero-state final
  float f[6] = {0.f, 0.f, 0.f, 0.f, 0.f, 0.f};
  v0.x = df2t_step(cf, f, v0.x); v0.y = df2t_step(cf, f, v0.y);
  v0.z = df2t_step(cf, f, v0.z); v0.w = df2t_step(cf, f, v0.w);
  v1.x = df2t_step(cf, f, v1.x); v1.y = df2t_step(cf, f, v1.y);
  v1.z = df2t_step(cf, f, v1.z); v1.w = df2t_step(cf, f, v1.w);
  v2.x = df2t_step(cf, f, v2.x); v2.y = df2t_step(cf, f, v2.y);
  v2.z = df2t_step(cf, f, v2.z); v2.w = df2t_step(cf, f, v2.w);
  v3.x = df2t_step(cf, f, v3.x); v3.y = df2t_step(cf, f, v3.y);
  v3.z = df2t_step(cf, f, v3.z); v3.w = df2t_step(cf, f, v3.w);
  v4.x = df2t_step(cf, f, v4.x); v4.y = df2t_step(cf, f, v4.y);
  v4.z = df2t_step(cf, f, v4.z); v4.w = df2t_step(cf, f, v4.w);

  // fold M*z0 into lane 0's f; zero-seeded scan then yields TRUE states
  if (lane == 0) tri_combine(f, mats, z0);
#pragma unroll
  for (int k = 0; k < 6; ++k) {
    float t6[6];
#pragma unroll
    for (int e = 0; e < 6; ++e) t6[e] = __shfl_up(f[e], 1 << k);
    if (lane >= (1 << k)) tri_combine(f, mats + k * 36, t6);
  }
  float zs[6];
#pragma unroll
  for (int e = 0; e < 6; ++e) {
    float tt = __shfl_up(f[e], 1);
    zs[e] = (lane == 0) ? z0[e] : tt;
  }

  // linear correction y = y_zero + g_t . zs -> own-wave LDS transpose rows
  const float* Gm = mats + 468;
  float* myrow = &Tr[w][lane * RST];
  auto corr = [&](int tl, float yz) {
    float a = yz;
#pragma unroll
    for (int e = 0; e < 6; ++e) a = fmaf(Gm[tl * 6 + e], zs[e], a);
    myrow[tl] = a;
  };
  corr(0, v0.x);  corr(1, v0.y);  corr(2, v0.z);  corr(3, v0.w);
  corr(4, v1.x);  corr(5, v1.y);  corr(6, v1.z);  corr(7, v1.w);
  corr(8, v2.x);  corr(9, v2.y);  corr(10, v2.z); corr(11, v2.w);
  corr(12, v3.x); corr(13, v3.y); corr(14, v3.z); corr(15, v3.w);
  corr(16, v4.x); corr(17, v4.y); corr(18, v4.z); corr(19, v4.w);
  __syncthreads();

  float* dst = y + base;
#pragma unroll
  for (int i2 = 0; i2 < NF4; ++i2) {
    int q = i2 * 64 + lane, k = q / NF4, m = q - k * NF4;
    vfloat4 w4;
    w4.x = Tr[w][k * RST + m * 4 + 0];
    w4.y = Tr[w][k * RST + m * 4 + 1];
    w4.z = Tr[w][k * RST + m * 4 + 2];
    w4.w = Tr[w][k * RST + m * 4 + 3];
    __builtin_nontemporal_store(w4, reinterpret_cast<vfloat4*>(dst + 4 * q));
  }
}

extern "C" void kernel_launch(void* const* d_in, const int* in_sizes, int n_in,
                              void* d_out, int out_size, void* d_ws, size_t ws_size,
                              hipStream_t stream) {
  const float* x = (const float*)d_in[0];
  const float* sos = (const float*)d_in[1];
  float* y = (float*)d_out;

  float* Fsup = (float*)d_ws;             // [NSC][6]
  float* zsup = Fsup + (size_t)NSC * 6;   // [NSC][6]
  float* mats = zsup + (size_t)NSC * 6;   // [588]

  hipLaunchKernelGGL(setup_kernel, dim3(1), dim3(64), 0, stream, sos, mats);
  hipLaunchKernelGGL(pass1_kernel, dim3(NSC / WPB), dim3(256), 0, stream, x, sos, mats, Fsup);
  hipLaunchKernelGGL(middle_scan, dim3(B_ROWS), dim3(64), 0, stream, Fsup, mats, zsup);
  hipLaunchKernelGGL(pass2_kernel, dim3(NSC / WPB), dim3(256), 0, stream, x, sos, mats, zsup, y);
}